// Round 7
// baseline (398.634 us; speedup 1.0000x reference)
//
#include <hip/hip_runtime.h>
#include <cstddef>
#include <cstdint>

#define GRID_S 8000
#define FDIM 512
#define NHEAD 8
#define HD 64
#define KNN 32
#define NB 4
#define M_TOT (NB * GRID_S)   // 32000

typedef __attribute__((ext_vector_type(8))) __bf16 bf16x8;
typedef __attribute__((ext_vector_type(4))) float f32x4;
typedef __attribute__((ext_vector_type(2))) float f32x2;
typedef __attribute__((ext_vector_type(2))) short short2v;

#if __has_builtin(__builtin_elementwise_fma)
#define FMA2(a,b,c) __builtin_elementwise_fma((a),(b),(c))
#else
#define FMA2(a,b,c) ((a)*(b)+(c))
#endif

#if __has_builtin(__builtin_amdgcn_fdot2_f32_bf16)
#define HAS_DOT2 1
#else
#define HAS_DOT2 0
#endif

// ---------------- helpers ----------------
__device__ inline ushort f2bf(float f) {            // RTN-even
    uint32_t u = __builtin_bit_cast(uint32_t, f);
    uint32_t r = (u + 0x7fffu + ((u >> 16) & 1u)) >> 16;
    return (ushort)r;
}
__device__ inline f32x2 unpk(uint32_t u) {
    f32x2 r;
    r.x = __builtin_bit_cast(float, u << 16);
    r.y = __builtin_bit_cast(float, u & 0xffff0000u);
    return r;
}

// ---------------- fused fp32->bf16 convert ----------------
#define NX4 (M_TOT * FDIM / 4)
#define NW4 (FDIM * FDIM / 4)

__global__ __launch_bounds__(256) void cvt_all(const float* __restrict__ x,
                                               const float* __restrict__ Wq,
                                               const float* __restrict__ Wk,
                                               const float* __restrict__ Wv,
                                               ushort* __restrict__ xb,
                                               ushort* __restrict__ wb) {
    int i = blockIdx.x * 256 + threadIdx.x;
    if (i < NX4) {
        float4 f = ((const float4*)x)[i];
        ushort4 o = { f2bf(f.x), f2bf(f.y), f2bf(f.z), f2bf(f.w) };
        ((ushort4*)xb)[i] = o;
        return;
    }
    i -= NX4;
    const int which = i >> 16;
    const int off = i & (NW4 - 1);
    const float* w = (which == 0) ? Wq : (which == 1) ? Wk : Wv;
    float4 f = ((const float4*)w)[off];
    ushort4 o = { f2bf(f.x), f2bf(f.y), f2bf(f.z), f2bf(f.w) };
    ((ushort4*)wb)[which * NW4 + off] = o;
}

// ---------------- fused QKV bf16 MFMA GEMM (q scaled by 0.125, all bf16 out) ----------
#define TBM 128
#define TBN 128
#define TBK 32

__device__ inline void gload_lds16(const ushort* g, ushort* l) {
    __builtin_amdgcn_global_load_lds((const __attribute__((address_space(1))) uint32_t*)g,
                                     (__attribute__((address_space(3))) uint32_t*)l,
                                     16, 0, 0);
}

__global__ __launch_bounds__(256) void gemm_qkv(const ushort* __restrict__ A,
                                                const ushort* __restrict__ B,
                                                ushort* __restrict__ qo,
                                                ushort* __restrict__ ko,
                                                ushort* __restrict__ vo) {
    __shared__ ushort As[TBM * TBK];
    __shared__ ushort Bs[TBN * TBK];
    const int tid = threadIdx.x;
    const int wv = tid >> 6;
    const int lane = tid & 63;
    const int bm = blockIdx.x * TBM;
    const int bn = blockIdx.y * TBN;
    const int wr = (wv >> 1) * 64;
    const int wc = (wv & 1) * 64;
    f32x4 acc[4][4] = {};

    const int srow = wv * 32 + (lane >> 2);
    const int scol = (lane & 3) * 8;
    const int fr = lane & 15;
    const int fk = (lane >> 4) * 8;

    for (int k0 = 0; k0 < FDIM; k0 += TBK) {
        const ushort* ga = A + (size_t)(bm + srow) * FDIM + k0 + scol;
        const ushort* gb = B + (size_t)(bn + srow) * FDIM + k0 + scol;
        gload_lds16(ga,             &As[(wv * 32) * TBK]);
        gload_lds16(ga + 16 * FDIM, &As[(wv * 32 + 16) * TBK]);
        gload_lds16(gb,             &Bs[(wv * 32) * TBK]);
        gload_lds16(gb + 16 * FDIM, &Bs[(wv * 32 + 16) * TBK]);
        __syncthreads();

        bf16x8 af[4], bfr[4];
        #pragma unroll
        for (int i = 0; i < 4; ++i) {
            af[i]  = *(const bf16x8*)&As[(wr + i * 16 + fr) * TBK + fk];
            bfr[i] = *(const bf16x8*)&Bs[(wc + i * 16 + fr) * TBK + fk];
        }
        #pragma unroll
        for (int i = 0; i < 4; ++i)
            #pragma unroll
            for (int j = 0; j < 4; ++j)
                acc[i][j] = __builtin_amdgcn_mfma_f32_16x16x32_bf16(af[i], bfr[j], acc[i][j], 0, 0, 0);
        __syncthreads();
    }

    const int cr = (lane >> 4) * 4;
    const int cc = lane & 15;
    const int seg = blockIdx.y >> 2;
    const int cn = (blockIdx.y & 3) * TBN;
    ushort* dst = (seg == 0) ? qo : (seg == 1) ? ko : vo;
    const float scl = (seg == 0) ? 0.125f : 1.0f;
    #pragma unroll
    for (int i = 0; i < 4; ++i)
        #pragma unroll
        for (int j = 0; j < 4; ++j) {
            ushort* cp = dst + (size_t)(bm + wr + i * 16 + cr) * FDIM + cn + wc + j * 16 + cc;
            #pragma unroll
            for (int r = 0; r < 4; ++r)
                cp[(size_t)r * FDIM] = f2bf(acc[i][j][r] * scl);
        }
}

// ---------------- KNN attention v6: explicit register double-buffered pipeline ----------
// wave-per-s, no LDS, no barriers. Named A/B buffers keep 8 row-loads in flight
// at all times; v batch 0/1 issued before softmax math so it hides under VALU.
#define LD8(buf, bp, o)                                                          \
    _Pragma("unroll")                                                            \
    for (int _j = 0; _j < 8; ++_j)                                               \
        buf[_j] = *(const uint4*)((bp) + ((size_t)(uint32_t)nbi[(o) + _j] << 9));

#if HAS_DOT2
#define SCORE8(o, buf)                                                           \
    _Pragma("unroll")                                                            \
    for (int _j = 0; _j < 8; ++_j) {                                             \
        const uint4 kw = buf[_j];                                                \
        float p = __builtin_amdgcn_fdot2_f32_bf16(__builtin_bit_cast(short2v, kw.x), qs0, 0.f, false); \
        p = __builtin_amdgcn_fdot2_f32_bf16(__builtin_bit_cast(short2v, kw.y), qs1, p, false); \
        p = __builtin_amdgcn_fdot2_f32_bf16(__builtin_bit_cast(short2v, kw.z), qs2, p, false); \
        p = __builtin_amdgcn_fdot2_f32_bf16(__builtin_bit_cast(short2v, kw.w), qs3, p, false); \
        p += __shfl_xor(p, 1);                                                   \
        p += __shfl_xor(p, 2);                                                   \
        p += __shfl_xor(p, 4);                                                   \
        sc[(o) + _j] = p;                                                        \
    }
#else
#define SCORE8(o, buf)                                                           \
    _Pragma("unroll")                                                            \
    for (int _j = 0; _j < 8; ++_j) {                                             \
        const uint4 kw = buf[_j];                                                \
        f32x2 a2 = q2[0] * unpk(kw.x);                                           \
        a2 = FMA2(q2[1], unpk(kw.y), a2);                                        \
        a2 = FMA2(q2[2], unpk(kw.z), a2);                                        \
        a2 = FMA2(q2[3], unpk(kw.w), a2);                                        \
        float p = a2.x + a2.y;                                                   \
        p += __shfl_xor(p, 1);                                                   \
        p += __shfl_xor(p, 2);                                                   \
        p += __shfl_xor(p, 4);                                                   \
        sc[(o) + _j] = p;                                                        \
    }
#endif

#define ACC8(o, buf)                                                             \
    _Pragma("unroll")                                                            \
    for (int _j = 0; _j < 8; ++_j) {                                             \
        const uint4 vw = buf[_j];                                                \
        const float wgt = sc[(o) + _j];                                          \
        const f32x2 w2 = {wgt, wgt};                                             \
        acc[0] = FMA2(w2, unpk(vw.x), acc[0]);                                   \
        acc[1] = FMA2(w2, unpk(vw.y), acc[1]);                                   \
        acc[2] = FMA2(w2, unpk(vw.z), acc[2]);                                   \
        acc[3] = FMA2(w2, unpk(vw.w), acc[3]);                                   \
    }

__global__ __launch_bounds__(256) void knn_attn6(const ushort* __restrict__ q,
                                                 const ushort* __restrict__ k,
                                                 const ushort* __restrict__ v,
                                                 const int* __restrict__ nbr,
                                                 float* __restrict__ out) {
    const int bid = blockIdx.x;
    const int base = ((bid & 7) * (M_TOT / 32) + (bid >> 3)) * 4;   // bijective XCD swizzle
    const int lane = threadIdx.x & 63;
    const int wv = threadIdx.x >> 6;
    const int bs = base + wv;
    const int b = bs / GRID_S;
    const int s = bs - b * GRID_S;
    const int* __restrict__ nrow = nbr + s * KNN;   // wave-uniform -> scalar loads

    int nbi[KNN];
    #pragma unroll
    for (int j = 0; j < KNN; ++j) nbi[j] = nrow[j];

    const uint4 qw = *(const uint4*)(q + (size_t)bs * FDIM + 8 * lane);
#if HAS_DOT2
    const short2v qs0 = __builtin_bit_cast(short2v, qw.x);
    const short2v qs1 = __builtin_bit_cast(short2v, qw.y);
    const short2v qs2 = __builtin_bit_cast(short2v, qw.z);
    const short2v qs3 = __builtin_bit_cast(short2v, qw.w);
#else
    const f32x2 q2[4] = { unpk(qw.x), unpk(qw.y), unpk(qw.z), unpk(qw.w) };
#endif

    const ushort* kb = k + (size_t)b * GRID_S * FDIM + 8 * lane;
    const ushort* vb = v + (size_t)b * GRID_S * FDIM + 8 * lane;

    float sc[KNN];
    uint4 bufA[8], bufB[8], bufC[8];

    // ---- scoring: prefetch-next-8 while scoring current-8 ----
    LD8(bufA, kb, 0);
    LD8(bufB, kb, 8);
    SCORE8(0, bufA);
    LD8(bufA, kb, 16);
    SCORE8(8, bufB);
    LD8(bufB, kb, 24);
    SCORE8(16, bufA);
    LD8(bufC, vb, 0);          // v batch 0 in flight across softmax
    SCORE8(24, bufB);
    LD8(bufA, vb, 8);          // v batch 1 too

    // ---- per-lane register softmax (runs under the v-load latency) ----
    float mx = sc[0];
    #pragma unroll
    for (int j = 1; j < KNN; ++j) mx = fmaxf(mx, sc[j]);
    float sum = 0.f;
    #pragma unroll
    for (int j = 0; j < KNN; ++j) {
        sc[j] = __expf(sc[j] - mx);
        sum += sc[j];
    }
    const float inv = 1.0f / sum;

    // ---- PV: prefetch-while-accumulate ----
    f32x2 acc[4] = {};
    LD8(bufB, vb, 16);
    ACC8(0, bufC);
    LD8(bufC, vb, 24);
    ACC8(8, bufA);
    ACC8(16, bufB);
    ACC8(24, bufC);

    const f32x2 inv2 = {inv, inv};
    #pragma unroll
    for (int r = 0; r < 4; ++r) acc[r] *= inv2;

    float* op = out + (size_t)bs * FDIM + 8 * lane;
    float4 o0 = {acc[0].x, acc[0].y, acc[1].x, acc[1].y};
    float4 o1 = {acc[2].x, acc[2].y, acc[3].x, acc[3].y};
    *(float4*)op = o0;
    *(float4*)(op + 4) = o1;
}

extern "C" void kernel_launch(void* const* d_in, const int* in_sizes, int n_in,
                              void* d_out, int out_size, void* d_ws, size_t ws_size,
                              hipStream_t stream) {
    const float* x  = (const float*)d_in[0];
    const float* Wq = (const float*)d_in[1];
    const float* Wk = (const float*)d_in[2];
    const float* Wv = (const float*)d_in[3];
    const int*   nbr = (const int*)d_in[4];
    float* out = (float*)d_out;

    const size_t m_elems = (size_t)M_TOT * FDIM;
    const size_t w_elems = (size_t)FDIM * FDIM;

    ushort* xb  = (ushort*)d_ws;
    ushort* wb  = xb + m_elems;
    ushort* kbf = wb + 3 * w_elems;
    ushort* vbf = kbf + m_elems;
    ushort* qbf = vbf + m_elems;

    cvt_all<<<(NX4 + 3 * NW4) / 256, 256, 0, stream>>>(x, Wq, Wk, Wv, xb, wb);

    dim3 grid(M_TOT / TBM, 3 * FDIM / TBN);   // (250, 12)
    gemm_qkv<<<grid, 256, 0, stream>>>(xb, wb, qbf, kbf, vbf);

    knn_attn6<<<M_TOT / 4, 256, 0, stream>>>(qbf, kbf, vbf, nbr, out);
}

// Round 8
// 242.872 us; speedup vs baseline: 1.6413x; 1.6413x over previous
//
#include <hip/hip_runtime.h>
#include <cstddef>
#include <cstdint>

#define GRID_S 8000
#define FDIM 512
#define NHEAD 8
#define HD 64
#define KNN 32
#define NB 4
#define M_TOT (NB * GRID_S)   // 32000

typedef __attribute__((ext_vector_type(8))) __bf16 bf16x8;
typedef __attribute__((ext_vector_type(4))) float f32x4;
typedef __attribute__((ext_vector_type(2))) float f32x2;
typedef __attribute__((ext_vector_type(2))) short short2v;

#if __has_builtin(__builtin_elementwise_fma)
#define FMA2(a,b,c) __builtin_elementwise_fma((a),(b),(c))
#else
#define FMA2(a,b,c) ((a)*(b)+(c))
#endif

#if __has_builtin(__builtin_amdgcn_fdot2_f32_bf16)
#define HAS_DOT2 1
#else
#define HAS_DOT2 0
#endif

// ---------------- helpers ----------------
__device__ inline ushort f2bf(float f) {            // RTN-even
    uint32_t u = __builtin_bit_cast(uint32_t, f);
    uint32_t r = (u + 0x7fffu + ((u >> 16) & 1u)) >> 16;
    return (ushort)r;
}
__device__ inline f32x2 unpk(uint32_t u) {
    f32x2 r;
    r.x = __builtin_bit_cast(float, u << 16);
    r.y = __builtin_bit_cast(float, u & 0xffff0000u);
    return r;
}

// ---------------- fused fp32->bf16 convert ----------------
#define NX4 (M_TOT * FDIM / 4)
#define NW4 (FDIM * FDIM / 4)

__global__ __launch_bounds__(256) void cvt_all(const float* __restrict__ x,
                                               const float* __restrict__ Wq,
                                               const float* __restrict__ Wk,
                                               const float* __restrict__ Wv,
                                               ushort* __restrict__ xb,
                                               ushort* __restrict__ wb) {
    int i = blockIdx.x * 256 + threadIdx.x;
    if (i < NX4) {
        float4 f = ((const float4*)x)[i];
        ushort4 o = { f2bf(f.x), f2bf(f.y), f2bf(f.z), f2bf(f.w) };
        ((ushort4*)xb)[i] = o;
        return;
    }
    i -= NX4;
    const int which = i >> 16;
    const int off = i & (NW4 - 1);
    const float* w = (which == 0) ? Wq : (which == 1) ? Wk : Wv;
    float4 f = ((const float4*)w)[off];
    ushort4 o = { f2bf(f.x), f2bf(f.y), f2bf(f.z), f2bf(f.w) };
    ((ushort4*)wb)[which * NW4 + off] = o;
}

// ---------------- fused QKV bf16 MFMA GEMM (q scaled by 0.125, all bf16 out) ----------
#define TBM 128
#define TBN 128
#define TBK 32

__device__ inline void gload_lds16(const ushort* g, ushort* l) {
    __builtin_amdgcn_global_load_lds((const __attribute__((address_space(1))) uint32_t*)g,
                                     (__attribute__((address_space(3))) uint32_t*)l,
                                     16, 0, 0);
}

__global__ __launch_bounds__(256) void gemm_qkv(const ushort* __restrict__ A,
                                                const ushort* __restrict__ B,
                                                ushort* __restrict__ qo,
                                                ushort* __restrict__ ko,
                                                ushort* __restrict__ vo) {
    __shared__ ushort As[TBM * TBK];
    __shared__ ushort Bs[TBN * TBK];
    const int tid = threadIdx.x;
    const int wv = tid >> 6;
    const int lane = tid & 63;
    const int bm = blockIdx.x * TBM;
    const int bn = blockIdx.y * TBN;
    const int wr = (wv >> 1) * 64;
    const int wc = (wv & 1) * 64;
    f32x4 acc[4][4] = {};

    const int srow = wv * 32 + (lane >> 2);
    const int scol = (lane & 3) * 8;
    const int fr = lane & 15;
    const int fk = (lane >> 4) * 8;

    for (int k0 = 0; k0 < FDIM; k0 += TBK) {
        const ushort* ga = A + (size_t)(bm + srow) * FDIM + k0 + scol;
        const ushort* gb = B + (size_t)(bn + srow) * FDIM + k0 + scol;
        gload_lds16(ga,             &As[(wv * 32) * TBK]);
        gload_lds16(ga + 16 * FDIM, &As[(wv * 32 + 16) * TBK]);
        gload_lds16(gb,             &Bs[(wv * 32) * TBK]);
        gload_lds16(gb + 16 * FDIM, &Bs[(wv * 32 + 16) * TBK]);
        __syncthreads();

        bf16x8 af[4], bfr[4];
        #pragma unroll
        for (int i = 0; i < 4; ++i) {
            af[i]  = *(const bf16x8*)&As[(wr + i * 16 + fr) * TBK + fk];
            bfr[i] = *(const bf16x8*)&Bs[(wc + i * 16 + fr) * TBK + fk];
        }
        #pragma unroll
        for (int i = 0; i < 4; ++i)
            #pragma unroll
            for (int j = 0; j < 4; ++j)
                acc[i][j] = __builtin_amdgcn_mfma_f32_16x16x32_bf16(af[i], bfr[j], acc[i][j], 0, 0, 0);
        __syncthreads();
    }

    const int cr = (lane >> 4) * 4;
    const int cc = lane & 15;
    const int seg = blockIdx.y >> 2;
    const int cn = (blockIdx.y & 3) * TBN;
    ushort* dst = (seg == 0) ? qo : (seg == 1) ? ko : vo;
    const float scl = (seg == 0) ? 0.125f : 1.0f;
    #pragma unroll
    for (int i = 0; i < 4; ++i)
        #pragma unroll
        for (int j = 0; j < 4; ++j) {
            ushort* cp = dst + (size_t)(bm + wr + i * 16 + cr) * FDIM + cn + wc + j * 16 + cc;
            #pragma unroll
            for (int r = 0; r < 4; ++r)
                cp[(size_t)r * FDIM] = f2bf(acc[i][j][r] * scl);
        }
}

// ---------------- KNN attention v7: gather via global_load_lds DMA ----------------
// wave-per-s. Per wave: 2 LDS buffers x 8 rows x 1KB. 8 chunks (4 k, 4 v) flow
// through the buffers; global_load_lds keeps 8-16 row-loads in flight with zero
// VGPR cost; vmcnt(8) gates consumption, lgkmcnt(0) gates buffer reuse.
// All pipeline state is single-wave -> no barriers, no cross-wave races.
#define CH 8

#if HAS_DOT2
#define SCORE_CH(o, buf)                                                         \
    _Pragma("unroll")                                                            \
    for (int _r = 0; _r < CH; ++_r) {                                            \
        const uint4 kw = *(const uint4*)(mylds + ((buf) * CH + _r) * FDIM + 8 * lane); \
        float p = __builtin_amdgcn_fdot2_f32_bf16(__builtin_bit_cast(short2v, kw.x), qs0, 0.f, false); \
        p = __builtin_amdgcn_fdot2_f32_bf16(__builtin_bit_cast(short2v, kw.y), qs1, p, false); \
        p = __builtin_amdgcn_fdot2_f32_bf16(__builtin_bit_cast(short2v, kw.z), qs2, p, false); \
        p = __builtin_amdgcn_fdot2_f32_bf16(__builtin_bit_cast(short2v, kw.w), qs3, p, false); \
        p += __shfl_xor(p, 1);                                                   \
        p += __shfl_xor(p, 2);                                                   \
        p += __shfl_xor(p, 4);                                                   \
        sc[(o) + _r] = p;                                                        \
    }
#else
#define SCORE_CH(o, buf)                                                         \
    _Pragma("unroll")                                                            \
    for (int _r = 0; _r < CH; ++_r) {                                            \
        const uint4 kw = *(const uint4*)(mylds + ((buf) * CH + _r) * FDIM + 8 * lane); \
        f32x2 a2 = q2[0] * unpk(kw.x);                                           \
        a2 = FMA2(q2[1], unpk(kw.y), a2);                                        \
        a2 = FMA2(q2[2], unpk(kw.z), a2);                                        \
        a2 = FMA2(q2[3], unpk(kw.w), a2);                                        \
        float p = a2.x + a2.y;                                                   \
        p += __shfl_xor(p, 1);                                                   \
        p += __shfl_xor(p, 2);                                                   \
        p += __shfl_xor(p, 4);                                                   \
        sc[(o) + _r] = p;                                                        \
    }
#endif

#define ACC_CH(o, buf)                                                           \
    _Pragma("unroll")                                                            \
    for (int _r = 0; _r < CH; ++_r) {                                            \
        const uint4 vw = *(const uint4*)(mylds + ((buf) * CH + _r) * FDIM + 8 * lane); \
        const float wgt = sc[(o) + _r];                                          \
        const f32x2 w2 = {wgt, wgt};                                             \
        acc[0] = FMA2(w2, unpk(vw.x), acc[0]);                                   \
        acc[1] = FMA2(w2, unpk(vw.y), acc[1]);                                   \
        acc[2] = FMA2(w2, unpk(vw.z), acc[2]);                                   \
        acc[3] = FMA2(w2, unpk(vw.w), acc[3]);                                   \
    }

#define ISSUE_CH(buf, srcb, j0)                                                  \
    _Pragma("unroll")                                                            \
    for (int _r = 0; _r < CH; ++_r)                                              \
        gload_lds16((srcb) + ((size_t)(uint32_t)nbi[(j0) + _r] << 9) + 8 * lane, \
                    mylds + ((buf) * CH + _r) * FDIM);

#define WAITV8  asm volatile("s_waitcnt vmcnt(8)" ::: "memory")
#define WAITV0  asm volatile("s_waitcnt vmcnt(0)" ::: "memory")
#define WAITL0  asm volatile("s_waitcnt lgkmcnt(0)" ::: "memory")

__global__ __launch_bounds__(256) void knn_attn7(const ushort* __restrict__ q,
                                                 const ushort* __restrict__ k,
                                                 const ushort* __restrict__ v,
                                                 const int* __restrict__ nbr,
                                                 float* __restrict__ out) {
    __shared__ ushort lds[4][2][CH][FDIM];   // 64 KB; wave-private regions
    const int bid = blockIdx.x;
    const int base = ((bid & 7) * (M_TOT / 32) + (bid >> 3)) * 4;   // bijective XCD swizzle
    const int lane = threadIdx.x & 63;
    const int wv = threadIdx.x >> 6;
    const int bs = base + wv;
    const int b = bs / GRID_S;
    const int s = bs - b * GRID_S;
    const int* __restrict__ nrow = nbr + s * KNN;   // wave-uniform

    int nbi[KNN];
    #pragma unroll
    for (int j = 0; j < KNN; ++j) nbi[j] = nrow[j];

    const uint4 qw = *(const uint4*)(q + (size_t)bs * FDIM + 8 * lane);
#if HAS_DOT2
    const short2v qs0 = __builtin_bit_cast(short2v, qw.x);
    const short2v qs1 = __builtin_bit_cast(short2v, qw.y);
    const short2v qs2 = __builtin_bit_cast(short2v, qw.z);
    const short2v qs3 = __builtin_bit_cast(short2v, qw.w);
#else
    const f32x2 q2[4] = { unpk(qw.x), unpk(qw.y), unpk(qw.z), unpk(qw.w) };
#endif

    const ushort* kbase = k + (size_t)b * GRID_S * FDIM;
    const ushort* vbase = v + (size_t)b * GRID_S * FDIM;
    ushort* mylds = &lds[wv][0][0][0];

    float sc[KNN];

    // ---- k-phase: 4 chunks through 2 buffers ----
    ISSUE_CH(0, kbase, 0);
    ISSUE_CH(1, kbase, 8);
    WAITV8;  SCORE_CH(0, 0);   WAITL0;
    ISSUE_CH(0, kbase, 16);
    WAITV8;  SCORE_CH(8, 1);   WAITL0;
    ISSUE_CH(1, kbase, 24);
    WAITV8;  SCORE_CH(16, 0);  WAITL0;
    ISSUE_CH(0, vbase, 0);                 // v chunk 0 in flight
    WAITV8;  SCORE_CH(24, 1);  WAITL0;
    ISSUE_CH(1, vbase, 8);                 // v chunk 1 in flight

    // ---- per-lane register softmax (overlaps v0/v1 latency) ----
    float mx = sc[0];
    #pragma unroll
    for (int j = 1; j < KNN; ++j) mx = fmaxf(mx, sc[j]);
    float sum = 0.f;
    #pragma unroll
    for (int j = 0; j < KNN; ++j) {
        sc[j] = __expf(sc[j] - mx);
        sum += sc[j];
    }
    const float inv = 1.0f / sum;

    // ---- v-phase ----
    f32x2 acc[4] = {};
    WAITV8;  ACC_CH(0, 0);   WAITL0;
    ISSUE_CH(0, vbase, 16);
    WAITV8;  ACC_CH(8, 1);   WAITL0;
    ISSUE_CH(1, vbase, 24);
    WAITV8;  ACC_CH(16, 0);
    WAITV0;  ACC_CH(24, 1);

    const f32x2 inv2 = {inv, inv};
    #pragma unroll
    for (int r = 0; r < 4; ++r) acc[r] *= inv2;

    float* op = out + (size_t)bs * FDIM + 8 * lane;
    float4 o0 = {acc[0].x, acc[0].y, acc[1].x, acc[1].y};
    float4 o1 = {acc[2].x, acc[2].y, acc[3].x, acc[3].y};
    *(float4*)op = o0;
    *(float4*)(op + 4) = o1;
}

extern "C" void kernel_launch(void* const* d_in, const int* in_sizes, int n_in,
                              void* d_out, int out_size, void* d_ws, size_t ws_size,
                              hipStream_t stream) {
    const float* x  = (const float*)d_in[0];
    const float* Wq = (const float*)d_in[1];
    const float* Wk = (const float*)d_in[2];
    const float* Wv = (const float*)d_in[3];
    const int*   nbr = (const int*)d_in[4];
    float* out = (float*)d_out;

    const size_t m_elems = (size_t)M_TOT * FDIM;
    const size_t w_elems = (size_t)FDIM * FDIM;

    ushort* xb  = (ushort*)d_ws;
    ushort* wb  = xb + m_elems;
    ushort* kbf = wb + 3 * w_elems;
    ushort* vbf = kbf + m_elems;
    ushort* qbf = vbf + m_elems;

    cvt_all<<<(NX4 + 3 * NW4) / 256, 256, 0, stream>>>(x, Wq, Wk, Wv, xb, wb);

    dim3 grid(M_TOT / TBM, 3 * FDIM / TBN);   // (250, 12)
    gemm_qkv<<<grid, 256, 0, stream>>>(xb, wb, qbf, kbf, vbf);

    knn_attn7<<<M_TOT / 4, 256, 0, stream>>>(qbf, kbf, vbf, nbr, out);
}

// Round 9
// 218.000 us; speedup vs baseline: 1.8286x; 1.1141x over previous
//
#include <hip/hip_runtime.h>
#include <cstddef>
#include <cstdint>

#define GRID_S 8000
#define FDIM 512
#define NHEAD 8
#define HD 64
#define KNN 32
#define NB 4
#define M_TOT (NB * GRID_S)   // 32000

typedef __attribute__((ext_vector_type(8))) __bf16 bf16x8;
typedef __attribute__((ext_vector_type(4))) float f32x4;
typedef __attribute__((ext_vector_type(2))) float f32x2;
typedef __attribute__((ext_vector_type(2))) short short2v;

#if __has_builtin(__builtin_elementwise_fma)
#define FMA2(a,b,c) __builtin_elementwise_fma((a),(b),(c))
#else
#define FMA2(a,b,c) ((a)*(b)+(c))
#endif

#if __has_builtin(__builtin_amdgcn_fdot2_f32_bf16)
#define HAS_DOT2 1
#else
#define HAS_DOT2 0
#endif

// ---------------- helpers ----------------
__device__ inline ushort f2bf(float f) {            // RTN-even
    uint32_t u = __builtin_bit_cast(uint32_t, f);
    uint32_t r = (u + 0x7fffu + ((u >> 16) & 1u)) >> 16;
    return (ushort)r;
}
__device__ inline f32x2 unpk(uint32_t u) {
    f32x2 r;
    r.x = __builtin_bit_cast(float, u << 16);
    r.y = __builtin_bit_cast(float, u & 0xffff0000u);
    return r;
}

// ---------------- fused fp32->bf16 convert ----------------
#define NX4 (M_TOT * FDIM / 4)
#define NW4 (FDIM * FDIM / 4)

__global__ __launch_bounds__(256) void cvt_all(const float* __restrict__ x,
                                               const float* __restrict__ Wq,
                                               const float* __restrict__ Wk,
                                               const float* __restrict__ Wv,
                                               ushort* __restrict__ xb,
                                               ushort* __restrict__ wb) {
    int i = blockIdx.x * 256 + threadIdx.x;
    if (i < NX4) {
        float4 f = ((const float4*)x)[i];
        ushort4 o = { f2bf(f.x), f2bf(f.y), f2bf(f.z), f2bf(f.w) };
        ((ushort4*)xb)[i] = o;
        return;
    }
    i -= NX4;
    const int which = i >> 16;
    const int off = i & (NW4 - 1);
    const float* w = (which == 0) ? Wq : (which == 1) ? Wk : Wv;
    float4 f = ((const float4*)w)[off];
    ushort4 o = { f2bf(f.x), f2bf(f.y), f2bf(f.z), f2bf(f.w) };
    ((ushort4*)wb)[which * NW4 + off] = o;
}

// ---------------- fused QKV bf16 MFMA GEMM ----------------
// q (scaled 0.125) -> qo [32000][512]; k/v -> interleaved kvo [32000][1024]
// (k at row offset 0, v at row offset 512).
#define TBM 128
#define TBN 128
#define TBK 32

__device__ inline void gload_lds16(const ushort* g, ushort* l) {
    __builtin_amdgcn_global_load_lds((const __attribute__((address_space(1))) uint32_t*)g,
                                     (__attribute__((address_space(3))) uint32_t*)l,
                                     16, 0, 0);
}

__global__ __launch_bounds__(256) void gemm_qkv(const ushort* __restrict__ A,
                                                const ushort* __restrict__ B,
                                                ushort* __restrict__ qo,
                                                ushort* __restrict__ kvo) {
    __shared__ ushort As[TBM * TBK];
    __shared__ ushort Bs[TBN * TBK];
    const int tid = threadIdx.x;
    const int wv = tid >> 6;
    const int lane = tid & 63;
    const int bm = blockIdx.x * TBM;
    const int bn = blockIdx.y * TBN;
    const int wr = (wv >> 1) * 64;
    const int wc = (wv & 1) * 64;
    f32x4 acc[4][4] = {};

    const int srow = wv * 32 + (lane >> 2);
    const int scol = (lane & 3) * 8;
    const int fr = lane & 15;
    const int fk = (lane >> 4) * 8;

    for (int k0 = 0; k0 < FDIM; k0 += TBK) {
        const ushort* ga = A + (size_t)(bm + srow) * FDIM + k0 + scol;
        const ushort* gb = B + (size_t)(bn + srow) * FDIM + k0 + scol;
        gload_lds16(ga,             &As[(wv * 32) * TBK]);
        gload_lds16(ga + 16 * FDIM, &As[(wv * 32 + 16) * TBK]);
        gload_lds16(gb,             &Bs[(wv * 32) * TBK]);
        gload_lds16(gb + 16 * FDIM, &Bs[(wv * 32 + 16) * TBK]);
        __syncthreads();

        bf16x8 af[4], bfr[4];
        #pragma unroll
        for (int i = 0; i < 4; ++i) {
            af[i]  = *(const bf16x8*)&As[(wr + i * 16 + fr) * TBK + fk];
            bfr[i] = *(const bf16x8*)&Bs[(wc + i * 16 + fr) * TBK + fk];
        }
        #pragma unroll
        for (int i = 0; i < 4; ++i)
            #pragma unroll
            for (int j = 0; j < 4; ++j)
                acc[i][j] = __builtin_amdgcn_mfma_f32_16x16x32_bf16(af[i], bfr[j], acc[i][j], 0, 0, 0);
        __syncthreads();
    }

    const int cr = (lane >> 4) * 4;
    const int cc = lane & 15;
    const int seg = blockIdx.y >> 2;                 // 0=q, 1=k, 2=v
    const int cn = (blockIdx.y & 3) * TBN;
    if (seg == 0) {
        #pragma unroll
        for (int i = 0; i < 4; ++i)
            #pragma unroll
            for (int j = 0; j < 4; ++j) {
                ushort* cp = qo + (size_t)(bm + wr + i * 16 + cr) * FDIM + cn + wc + j * 16 + cc;
                #pragma unroll
                for (int r = 0; r < 4; ++r)
                    cp[(size_t)r * FDIM] = f2bf(acc[i][j][r] * 0.125f);
            }
    } else {
        ushort* base = kvo + ((seg == 2) ? FDIM : 0);
        #pragma unroll
        for (int i = 0; i < 4; ++i)
            #pragma unroll
            for (int j = 0; j < 4; ++j) {
                ushort* cp = base + (size_t)(bm + wr + i * 16 + cr) * (2 * FDIM) + cn + wc + j * 16 + cc;
                #pragma unroll
                for (int r = 0; r < 4; ++r)
                    cp[(size_t)r * (2 * FDIM)] = f2bf(acc[i][j][r]);
            }
    }
}

// ---------------- KNN attention v8: interleaved kv rows + online softmax ----------------
// wave-per-s, zero LDS, zero barriers (v4 skeleton). One address stream: neighbor j's
// k-row and v-row live in one 2KB row (v at +1024B immediate offset). Online softmax
// (defer-rescale, thr=8) removes sc[32] storage and the k/v phase join -> one streaming
// loop the compiler can pipeline with the freed registers.
__global__ __launch_bounds__(256) void knn_attn8(const ushort* __restrict__ q,
                                                 const ushort* __restrict__ kv,
                                                 const int* __restrict__ nbr,
                                                 float* __restrict__ out) {
    const int bid = blockIdx.x;
    const int base = ((bid & 7) * (M_TOT / 32) + (bid >> 3)) * 4;   // bijective XCD swizzle
    const int lane = threadIdx.x & 63;
    const int wv = threadIdx.x >> 6;
    const int bs = base + wv;
    const int b = bs / GRID_S;
    const int s = bs - b * GRID_S;
    const int* __restrict__ nrow = nbr + s * KNN;   // wave-uniform -> scalar loads

    const uint4 qw = *(const uint4*)(q + (size_t)bs * FDIM + 8 * lane);
#if HAS_DOT2
    const short2v qs0 = __builtin_bit_cast(short2v, qw.x);
    const short2v qs1 = __builtin_bit_cast(short2v, qw.y);
    const short2v qs2 = __builtin_bit_cast(short2v, qw.z);
    const short2v qs3 = __builtin_bit_cast(short2v, qw.w);
#else
    const f32x2 q2[4] = { unpk(qw.x), unpk(qw.y), unpk(qw.z), unpk(qw.w) };
#endif

    const ushort* kvb = kv + (size_t)b * GRID_S * (2 * FDIM) + 8 * lane;

#if HAS_DOT2
#define SCORE1(kw, p)                                                                     \
    p = __builtin_amdgcn_fdot2_f32_bf16(__builtin_bit_cast(short2v, kw.x), qs0, 0.f, false); \
    p = __builtin_amdgcn_fdot2_f32_bf16(__builtin_bit_cast(short2v, kw.y), qs1, p, false);   \
    p = __builtin_amdgcn_fdot2_f32_bf16(__builtin_bit_cast(short2v, kw.z), qs2, p, false);   \
    p = __builtin_amdgcn_fdot2_f32_bf16(__builtin_bit_cast(short2v, kw.w), qs3, p, false);   \
    p += __shfl_xor(p, 1); p += __shfl_xor(p, 2); p += __shfl_xor(p, 4);
#else
#define SCORE1(kw, p)                                                                     \
    {                                                                                     \
        f32x2 a2 = q2[0] * unpk(kw.x);                                                    \
        a2 = FMA2(q2[1], unpk(kw.y), a2);                                                 \
        a2 = FMA2(q2[2], unpk(kw.z), a2);                                                 \
        a2 = FMA2(q2[3], unpk(kw.w), a2);                                                 \
        p = a2.x + a2.y;                                                                  \
    }                                                                                     \
    p += __shfl_xor(p, 1); p += __shfl_xor(p, 2); p += __shfl_xor(p, 4);
#endif

    float m, sum;
    f32x2 acc[4];
    {   // j = 0: w = 1 exactly
        const ushort* rp = kvb + ((size_t)(uint32_t)nrow[0] << 10);
        const uint4 kw = *(const uint4*)rp;
        const uint4 vw = *(const uint4*)(rp + FDIM);
        float p;
        SCORE1(kw, p);
        m = p;
        sum = 1.f;
        acc[0] = unpk(vw.x);
        acc[1] = unpk(vw.y);
        acc[2] = unpk(vw.z);
        acc[3] = unpk(vw.w);
    }
    #pragma unroll
    for (int j = 1; j < KNN; ++j) {
        const ushort* rp = kvb + ((size_t)(uint32_t)nrow[j] << 10);
        const uint4 kw = *(const uint4*)rp;
        const uint4 vw = *(const uint4*)(rp + FDIM);
        float p;
        SCORE1(kw, p);
        if (__any(p - m > 8.f)) {        // rare wave-uniform rescale (T13 defer-max)
            const float nm = fmaxf(m, p);
            const float c = __expf(m - nm);
            const f32x2 c2 = {c, c};
            sum *= c;
            acc[0] *= c2; acc[1] *= c2; acc[2] *= c2; acc[3] *= c2;
            m = nm;
        }
        const float w = __expf(p - m);
        sum += w;
        const f32x2 w2 = {w, w};
        acc[0] = FMA2(w2, unpk(vw.x), acc[0]);
        acc[1] = FMA2(w2, unpk(vw.y), acc[1]);
        acc[2] = FMA2(w2, unpk(vw.z), acc[2]);
        acc[3] = FMA2(w2, unpk(vw.w), acc[3]);
    }

    const float inv = 1.0f / sum;
    const f32x2 inv2 = {inv, inv};
    #pragma unroll
    for (int r = 0; r < 4; ++r) acc[r] *= inv2;

    float* op = out + (size_t)bs * FDIM + 8 * lane;
    float4 o0 = {acc[0].x, acc[0].y, acc[1].x, acc[1].y};
    float4 o1 = {acc[2].x, acc[2].y, acc[3].x, acc[3].y};
    *(float4*)op = o0;
    *(float4*)(op + 4) = o1;
#undef SCORE1
}

extern "C" void kernel_launch(void* const* d_in, const int* in_sizes, int n_in,
                              void* d_out, int out_size, void* d_ws, size_t ws_size,
                              hipStream_t stream) {
    const float* x  = (const float*)d_in[0];
    const float* Wq = (const float*)d_in[1];
    const float* Wk = (const float*)d_in[2];
    const float* Wv = (const float*)d_in[3];
    const int*   nbr = (const int*)d_in[4];
    float* out = (float*)d_out;

    const size_t m_elems = (size_t)M_TOT * FDIM;   // 16,384,000
    const size_t w_elems = (size_t)FDIM * FDIM;    // 262,144

    // workspace (bf16): xb 32MB, wb 1.5MB, kv 64MB, q 32MB  ~= 130MB
    ushort* xb  = (ushort*)d_ws;
    ushort* wb  = xb + m_elems;
    ushort* kvb = wb + 3 * w_elems;
    ushort* qbf = kvb + 2 * m_elems;

    cvt_all<<<(NX4 + 3 * NW4) / 256, 256, 0, stream>>>(x, Wq, Wk, Wv, xb, wb);

    dim3 grid(M_TOT / TBM, 3 * FDIM / TBN);   // (250, 12)
    gemm_qkv<<<grid, 256, 0, stream>>>(xb, wb, qbf, kvb);

    knn_attn8<<<M_TOT / 4, 256, 0, stream>>>(qbf, kvb, nbr, out);
}